// Round 10
// baseline (909.189 us; speedup 1.0000x reference)
//
#include <hip/hip_runtime.h>

using u16 = unsigned short;
using u32 = unsigned int;

#define H 256
#define NNODE 50000
#define CAP 32          // Poisson(6): P(deg>32) ~ 1e-15
#define FINK 1280
#define CHUNK 25088     // proj row chunk (196*128); chunk2 = 24912

// segmented LDS geometry for gemm_k32
#define ASEG 2080       // bytes per A k-segment (128 rows x 16B + 32B skew)
#define BSEG 4128       // bytes per B k-segment (256 rows x 16B + 32B skew)

typedef __attribute__((ext_vector_type(8))) short bf16x8;
typedef __attribute__((ext_vector_type(4))) float f32x4;

struct AChunks { const void* p[5]; };   // each chunk covers 256 k-elems

__device__ __forceinline__ u16 f2b(float f) {        // f32 -> bf16 RNE
    u32 u = __builtin_bit_cast(u32, f);
    return (u16)((u + 0x7FFFu + ((u >> 16) & 1u)) >> 16);
}
__device__ __forceinline__ float b2f(u16 h) {
    u32 u = ((u32)h) << 16;
    return __builtin_bit_cast(float, u);
}
__device__ __forceinline__ void gld_lds16(const void* g, void* l) {
    __builtin_amdgcn_global_load_lds(
        (__attribute__((address_space(1))) void*)(void*)g,
        (__attribute__((address_space(3))) void*)l, 16, 0, 0);
}
__device__ __forceinline__ u32 packbf(float a, float b) {
    return (u32)f2b(a) | ((u32)f2b(b) << 16);
}

// ---------------------------------------------------------------------------
// Unified bf16 MFMA GEMM: C[M,256] = concat_K(A)[M,Ktot] @ Bw[256,Ktot]^T + bias
// BM=128, BN=256 (B staged once per m-block), BK=32, 512 thr (8 waves 2m x 4n),
// dbuf LDS 48.5 KB (3 blocks/CU), vmcnt(3) 2-deep prefetch.
// LDS layout: segment per k-subslice ks=(lane>>4): A [4][128 rows][16B] stride
// ASEG, B [4][256 rows][16B] stride BSEG. Odd strides de-phase bank groups;
// gld_lds dest is wave-linear (segment boundary aligns with wave boundary).
// ---------------------------------------------------------------------------
template<bool RELU>
__global__ __launch_bounds__(512) void gemm_k32(
    AChunks ac, int aStride, const u16* __restrict__ Bw,
    const float* __restrict__ bias, u16* __restrict__ C, int M, int Ktot)
{
    __shared__ __align__(16) char As[2][4 * ASEG];
    __shared__ __align__(16) char Bs[2][4 * BSEG];

    const int tid = threadIdx.x;
    const int l   = tid & 63;
    const int w   = tid >> 6;            // 0..7
    const int wr  = w >> 2, wc = w & 3;  // 2m x 4n
    const int m0  = blockIdx.x * 128;
    const int nk  = Ktot >> 5;           // 16 / 24 / 40

    f32x4 acc[4][4];
#pragma unroll
    for (int i = 0; i < 4; ++i)
#pragma unroll
        for (int j = 0; j < 4; ++j) acc[i][j] = f32x4{0.f, 0.f, 0.f, 0.f};

    auto stageA = [&](int k, int bi) {
        int k0 = k * 32;
        const u16* base = (const u16*)ac.p[k0 >> 8];
        int kk = k0 & 255;
        int ks = tid >> 7, r = tid & 127;          // 512 chunks: [4 ks][128 r]
        int row = m0 + r; row = row < M ? row : M - 1;
        const u16* g = base + (size_t)row * aStride + kk + ks * 8;
        gld_lds16(g, &As[bi][ks * ASEG + r * 16]);
    };
    auto stageB = [&](int k, int bi) {
        int k0 = k * 32;
#pragma unroll
        for (int i = 0; i < 2; ++i) {
            int ci = i * 512 + tid;                // 1024 chunks: [4 ks][256 r]
            int ks = ci >> 8, r = ci & 255;
            const u16* g = Bw + (size_t)r * Ktot + k0 + ks * 8;
            gld_lds16(g, &Bs[bi][ks * BSEG + r * 16]);
        }
    };
    auto compute = [&](int bi) {
        const int ksl = l >> 4;
        bf16x8 af[4], bfr[4];
#pragma unroll
        for (int mi = 0; mi < 4; ++mi) {
            int r = wr * 64 + mi * 16 + (l & 15);
            af[mi] = *(const bf16x8*)&As[bi][ksl * ASEG + r * 16];
        }
#pragma unroll
        for (int ni = 0; ni < 4; ++ni) {
            int r = wc * 64 + ni * 16 + (l & 15);
            bfr[ni] = *(const bf16x8*)&Bs[bi][ksl * BSEG + r * 16];
        }
#pragma unroll
        for (int mi = 0; mi < 4; ++mi)
#pragma unroll
            for (int ni = 0; ni < 4; ++ni)
                acc[mi][ni] = __builtin_amdgcn_mfma_f32_16x16x32_bf16(
                    af[mi], bfr[ni], acc[mi][ni], 0, 0, 0);
    };
    auto body = [&](int k, int cur) {
        asm volatile("s_waitcnt vmcnt(3)" ::: "memory");   // stage(k) landed
        __builtin_amdgcn_sched_barrier(0);
        __builtin_amdgcn_s_barrier();
        __builtin_amdgcn_sched_barrier(0);
        compute(cur);
        __builtin_amdgcn_sched_barrier(0);
        __builtin_amdgcn_s_barrier();
        __builtin_amdgcn_sched_barrier(0);
        int kq = k + 2; if (kq > nk - 1) kq = nk - 1;      // clamped dup keeps count
        stageB(kq, cur);
        stageA(kq, cur);
        __builtin_amdgcn_sched_barrier(0);
    };

    stageB(0, 0); stageA(0, 0);
    __builtin_amdgcn_sched_barrier(0);
    stageB(1, 1); stageA(1, 1);
    __builtin_amdgcn_sched_barrier(0);
    for (int k = 0; k < nk; k += 2) {   // nk even for all our shapes
        body(k,     0);
        body(k + 1, 1);
    }
    asm volatile("s_waitcnt vmcnt(0)" ::: "memory");       // drain

    // epilogue: C/D layout col=lane&15, row=(lane>>4)*4+reg
    const int fr = l & 15, fq = l >> 4;
#pragma unroll
    for (int ni = 0; ni < 4; ++ni) {
        int col = wc * 64 + ni * 16 + fr;
        float bv = bias[col];
#pragma unroll
        for (int mi = 0; mi < 4; ++mi) {
            int rowb = m0 + wr * 64 + mi * 16 + fq * 4;
#pragma unroll
            for (int j = 0; j < 4; ++j) {
                int row = rowb + j;
                if (row < M) {
                    float v = acc[mi][ni][j] + bv;
                    if (RELU) v = fmaxf(v, 0.f);
                    C[(size_t)row * H + col] = f2b(v);
                }
            }
        }
    }
}

// ---------------------------------------------------------------------------
// streaming f32 -> bf16 convert (PROVEN 6.8 TB/s in R6)
// ---------------------------------------------------------------------------
__global__ __launch_bounds__(256) void cvt_f32_bf16(
    const float* __restrict__ in, u16* __restrict__ outp, size_t n8)
{
    size_t i = (size_t)blockIdx.x * blockDim.x + threadIdx.x;
    size_t stride = (size_t)gridDim.x * blockDim.x;
    for (; i < n8; i += stride) {
        const float4* s = (const float4*)(in + i * 8);
        float4 v0 = s[0], v1 = s[1];
        uint4 o;
        o.x = packbf(v0.x, v0.y);
        o.y = packbf(v0.z, v0.w);
        o.z = packbf(v1.x, v1.y);
        o.w = packbf(v1.z, v1.w);
        *(uint4*)(outp + i * 8) = o;
    }
}

// ---------------------------------------------------------------------------
// utility kernels
// ---------------------------------------------------------------------------
__global__ __launch_bounds__(256) void fill_zero(float4* __restrict__ p, size_t n4)
{
    size_t i = (size_t)blockIdx.x * blockDim.x + threadIdx.x;
    size_t stride = (size_t)gridDim.x * blockDim.x;
    for (; i < n4; i += stride) p[i] = make_float4(0.f, 0.f, 0.f, 0.f);
}

__global__ __launch_bounds__(256) void build_bucket(
    const int* __restrict__ src, const int* __restrict__ dst, int nE,
    int* __restrict__ cnt, int* __restrict__ bucket)
{
    int i = blockIdx.x * blockDim.x + threadIdx.x;
    if (i >= nE) return;
    int d = dst[i];
    int pos = atomicAdd(&cnt[d], 1);
    if (pos < CAP) bucket[(size_t)d * CAP + pos] = src[i];
}

__global__ __launch_bounds__(256) void seg_mean_gather(
    const u16* __restrict__ feat, const int* __restrict__ bucket,
    const int* __restrict__ cnt, int n_dst, u16* __restrict__ out)
{
    int d = (int)(((size_t)blockIdx.x * blockDim.x + threadIdx.x) >> 6);
    int lane = threadIdx.x & 63;
    if (d >= n_dst) return;
    int c = cnt[d];
    int cc = c < CAP ? c : CAP;
    const int* b = bucket + (size_t)d * CAP;
    float a0 = 0.f, a1 = 0.f, a2 = 0.f, a3 = 0.f;
    int i = 0;
    for (; i + 4 <= cc; i += 4) {            // 4 gathers in flight
        int s0 = b[i], s1 = b[i + 1], s2 = b[i + 2], s3 = b[i + 3];
        uint2 v0 = *(const uint2*)(feat + (size_t)s0 * H + lane * 4);
        uint2 v1 = *(const uint2*)(feat + (size_t)s1 * H + lane * 4);
        uint2 v2 = *(const uint2*)(feat + (size_t)s2 * H + lane * 4);
        uint2 v3 = *(const uint2*)(feat + (size_t)s3 * H + lane * 4);
        a0 += b2f((u16)(v0.x & 0xffff)) + b2f((u16)(v1.x & 0xffff))
            + b2f((u16)(v2.x & 0xffff)) + b2f((u16)(v3.x & 0xffff));
        a1 += b2f((u16)(v0.x >> 16)) + b2f((u16)(v1.x >> 16))
            + b2f((u16)(v2.x >> 16)) + b2f((u16)(v3.x >> 16));
        a2 += b2f((u16)(v0.y & 0xffff)) + b2f((u16)(v1.y & 0xffff))
            + b2f((u16)(v2.y & 0xffff)) + b2f((u16)(v3.y & 0xffff));
        a3 += b2f((u16)(v0.y >> 16)) + b2f((u16)(v1.y >> 16))
            + b2f((u16)(v2.y >> 16)) + b2f((u16)(v3.y >> 16));
    }
    for (; i < cc; ++i) {
        uint2 v = *(const uint2*)(feat + (size_t)b[i] * H + lane * 4);
        a0 += b2f((u16)(v.x & 0xffff));
        a1 += b2f((u16)(v.x >> 16));
        a2 += b2f((u16)(v.y & 0xffff));
        a3 += b2f((u16)(v.y >> 16));
    }
    float inv = 1.0f / fmaxf((float)c, 1.0f);
    uint2 o;
    o.x = packbf(a0 * inv, a1 * inv);
    o.y = packbf(a2 * inv, a3 * inv);
    *(uint2*)(out + (size_t)d * H + lane * 4) = o;
}

// 2 edges per wave: 32 lanes x 16B per edge row
__global__ __launch_bounds__(256) void edge_dot(
    const u16* __restrict__ P, const u16* __restrict__ Q,
    const int* __restrict__ ia, const int* __restrict__ ib,
    int nE, float* __restrict__ out)
{
    int gi = blockIdx.x * 256 + threadIdx.x;
    int e = gi >> 5, l32 = gi & 31;
    if (e >= nE) return;
    uint4 a = *(const uint4*)(P + (size_t)ia[e] * H + l32 * 8);
    uint4 b = *(const uint4*)(Q + (size_t)ib[e] * H + l32 * 8);
    float v = 0.f;
    v += b2f((u16)(a.x & 0xffff)) * b2f((u16)(b.x & 0xffff));
    v += b2f((u16)(a.x >> 16))    * b2f((u16)(b.x >> 16));
    v += b2f((u16)(a.y & 0xffff)) * b2f((u16)(b.y & 0xffff));
    v += b2f((u16)(a.y >> 16))    * b2f((u16)(b.y >> 16));
    v += b2f((u16)(a.z & 0xffff)) * b2f((u16)(b.z & 0xffff));
    v += b2f((u16)(a.z >> 16))    * b2f((u16)(b.z >> 16));
    v += b2f((u16)(a.w & 0xffff)) * b2f((u16)(b.w & 0xffff));
    v += b2f((u16)(a.w >> 16))    * b2f((u16)(b.w >> 16));
#pragma unroll
    for (int off = 16; off; off >>= 1) v += __shfl_xor(v, off);
    if (l32 == 0) out[e] = v;
}

// fused weight pack: 12 items, 1024 elems per block
struct PackTab {
    const float* s1[12]; const float* s2[12]; u16* dst[12];
    int Ks[12], Kdst[12], koff[12], blk0[13];
};
__global__ __launch_bounds__(256) void pack_all(PackTab t)
{
    int b = blockIdx.x;
    int it = 0;
    while (it < 11 && b >= t.blk0[it + 1]) ++it;
    int idx = (b - t.blk0[it]) * 1024 + threadIdx.x * 4;
    int Ks = t.Ks[it];
    if (idx >= 256 * Ks) return;
    int n = idx / Ks;
    int k = idx - n * Ks;
    float4 v = *(const float4*)(t.s1[it] + idx);
    if (t.s2[it]) {
        float4 u = *(const float4*)(t.s2[it] + idx);
        v.x += u.x; v.y += u.y; v.z += u.z; v.w += u.w;
    }
    ushort4 h;
    h.x = f2b(v.x); h.y = f2b(v.y); h.z = f2b(v.z); h.w = f2b(v.w);
    *(ushort4*)(t.dst[it] + (size_t)n * t.Kdst[it] + t.koff[it] + k) = h;
}

__global__ void bias_pair(const float* __restrict__ bl1, const float* __restrict__ bl2,
                          float* __restrict__ bq1, float* __restrict__ bq2)
{
    int i = threadIdx.x;
    if (blockIdx.x == 0) bq1[i] = bl1[i] + bl1[512 + i];
    else                 bq2[i] = bl2[i] + bl2[512 + i];
}

// ---------------------------------------------------------------------------
// host-side helpers
// ---------------------------------------------------------------------------
static inline void launch_gemm3(const void* a0, const void* a1, const void* a2,
                                const u16* Bw, const float* bias, u16* C,
                                int Ktot, bool relu, hipStream_t s)
{
    AChunks ac = {{a0, a1, a2, nullptr, nullptr}};
    dim3 grid((NNODE + 127) / 128, 1);
    if (relu) gemm_k32<true><<<grid, 512, 0, s>>>(ac, 256, Bw, bias, C, NNODE, Ktot);
    else      gemm_k32<false><<<grid, 512, 0, s>>>(ac, 256, Bw, bias, C, NNODE, Ktot);
}

extern "C" void kernel_launch(void* const* d_in, const int* in_sizes, int n_in,
                              void* d_out, int out_size, void* d_ws, size_t ws_size,
                              hipStream_t stream)
{
    const float* x_pep  = (const float*)d_in[0];
    const float* x_prot = (const float*)d_in[1];
    const float* Wpep   = (const float*)d_in[2];
    const float* bpep   = (const float*)d_in[3];
    const float* Wprot  = (const float*)d_in[4];
    const float* bprot  = (const float*)d_in[5];
    const float* Wl1    = (const float*)d_in[6];
    const float* bl1    = (const float*)d_in[7];
    const float* Wr1    = (const float*)d_in[8];
    const float* Wl2    = (const float*)d_in[9];
    const float* bl2    = (const float*)d_in[10];
    const float* Wr2    = (const float*)d_in[11];
    const int* ei_pp    = (const int*)d_in[12];
    const int* ei_rp    = (const int*)d_in[13];
    const int* ei_prot  = (const int*)d_in[14];
    const int* eli_het  = (const int*)d_in[15];
    const int* eli_homo = (const int*)d_in[16];

    const int E  = in_sizes[12] / 2;   // 300000
    const int EL = in_sizes[15] / 2;   // 200000

    float* out = (float*)d_out;

    // ---- workspace carve (~372 MB of 1 GB) ----
    const size_t nodeElems = (size_t)NNODE * H;      // bf16 elems
    u16* bufA = (u16*)d_ws;            // h_pep  -> p2
    u16* bufB = bufA + nodeElems;      // h_prot -> q2
    u16* bufC = bufB + nodeElems;      // p1
    u16* bufD = bufC + nodeElems;      // q1
    u16* bufE = bufD + nodeElems;      // mean scratch 1
    u16* bufF = bufE + nodeElems;      // mean scratch 2
    u16* Bpep  = bufF + nodeElems;
    u16* Bprot = Bpep  + (size_t)256 * 1280;
    u16* Bp1   = Bprot + (size_t)256 * 1280;
    u16* Bq1   = Bp1   + (size_t)256 * 512;
    u16* Bp2   = Bq1   + (size_t)256 * 768;
    u16* Bq2   = Bp2   + (size_t)256 * 512;
    float* bq1 = (float*)(Bq2 + (size_t)256 * 768);
    float* bq2 = bq1 + 256;
    int* cntRP   = (int*)(bq2 + 256);
    int* cntPP   = cntRP + NNODE;
    int* cntPR   = cntPP + NNODE;
    int* bktRP   = cntPR + NNODE;
    int* bktPP   = bktRP + (size_t)NNODE * CAP;
    int* bktPR   = bktPP + (size_t)NNODE * CAP;
    u16* xb      = (u16*)(bktPR + (size_t)NNODE * CAP);  // CHUNK*1280 u16 = 64.2 MB, reused

    const size_t HH = (size_t)H * H;

    // ---- fused weight pack ----
    PackTab t{};
    int blk = 0, it = 0;
    auto add = [&](const float* s1, const float* s2, u16* d, int Ks, int Kd, int ko) {
        t.s1[it] = s1; t.s2[it] = s2; t.dst[it] = d;
        t.Ks[it] = Ks; t.Kdst[it] = Kd; t.koff[it] = ko;
        t.blk0[it] = blk; blk += (256 * Ks) / 1024; ++it;
    };
    add(Wpep,  nullptr, Bpep,  1280, 1280, 0);
    add(Wprot, nullptr, Bprot, 1280, 1280, 0);
    add(Wl1 + 1 * HH, nullptr,      Bp1, 256, 512, 0);
    add(Wr1 + 1 * HH, nullptr,      Bp1, 256, 512, 256);
    add(Wl1 + 0 * HH, nullptr,      Bq1, 256, 768, 0);
    add(Wl1 + 2 * HH, nullptr,      Bq1, 256, 768, 256);
    add(Wr1 + 0 * HH, Wr1 + 2 * HH, Bq1, 256, 768, 512);
    add(Wl2 + 1 * HH, nullptr,      Bp2, 256, 512, 0);
    add(Wr2 + 1 * HH, nullptr,      Bp2, 256, 512, 256);
    add(Wl2 + 0 * HH, nullptr,      Bq2, 256, 768, 0);
    add(Wl2 + 2 * HH, nullptr,      Bq2, 256, 768, 256);
    add(Wr2 + 0 * HH, Wr2 + 2 * HH, Bq2, 256, 768, 512);
    t.blk0[12] = blk;
    pack_all<<<blk, 256, 0, stream>>>(t);
    bias_pair<<<2, 256, 0, stream>>>(bl1, bl2, bq1, bq2);

    // ---- buckets: built ONCE per edge type, reused by both layers ----
    fill_zero<<<147, 256, 0, stream>>>((float4*)cntRP, (size_t)3 * NNODE / 4);
    build_bucket<<<(E + 255) / 256, 256, 0, stream>>>(ei_rp,   ei_rp + E,   E, cntRP, bktRP);
    build_bucket<<<(E + 255) / 256, 256, 0, stream>>>(ei_pp,   ei_pp + E,   E, cntPP, bktPP);
    build_bucket<<<(E + 255) / 256, 256, 0, stream>>>(ei_prot, ei_prot + E, E, cntPR, bktPR);

    // ---- input projections: L3-hot chunked convert + gemm ----
    // Chunk traffic (128 MB read + 64 MB write) < 256 MB L3 -> xb stays hot;
    // proj GEMM then stages A from L3 at ~6 TB/s (H-GEMM regime).
    {
        auto proj = [&](const float* x, const u16* Bw, const float* bias, u16* Cout) {
            int offs[3] = {0, CHUNK, NNODE};
            for (int c = 0; c < 2; ++c) {
                int r0 = offs[c], rows = offs[c + 1] - r0;
                cvt_f32_bf16<<<2048, 256, 0, stream>>>(
                    x + (size_t)r0 * FINK, xb, (size_t)rows * FINK / 8);
                AChunks ac = {{xb, xb + 256, xb + 512, xb + 768, xb + 1024}};
                dim3 grid((rows + 127) / 128, 1);
                gemm_k32<false><<<grid, 512, 0, stream>>>(
                    ac, FINK, Bw, bias, Cout + (size_t)r0 * H, rows, FINK);
            }
        };
        proj(x_pep,  Bpep,  bpep,  bufA);
        proj(x_prot, Bprot, bprot, bufB);
    }

    const int gG = (NNODE * 64 + 255) / 256;
    // ---- layer 1 ----
    seg_mean_gather<<<gG, 256, 0, stream>>>(bufB, bktRP, cntRP, NNODE, bufE);
    launch_gemm3(bufE, bufA, nullptr, Bp1, bl1 + 256, bufC, 512, true, stream);
    seg_mean_gather<<<gG, 256, 0, stream>>>(bufA, bktPP, cntPP, NNODE, bufE);
    seg_mean_gather<<<gG, 256, 0, stream>>>(bufB, bktPR, cntPR, NNODE, bufF);
    launch_gemm3(bufE, bufF, bufB, Bq1, bq1, bufD, 768, true, stream);

    // ---- layer 2 ----
    seg_mean_gather<<<gG, 256, 0, stream>>>(bufD, bktRP, cntRP, NNODE, bufE);
    launch_gemm3(bufE, bufC, nullptr, Bp2, bl2 + 256, bufA, 512, false, stream);
    seg_mean_gather<<<gG, 256, 0, stream>>>(bufC, bktPP, cntPP, NNODE, bufE);
    seg_mean_gather<<<gG, 256, 0, stream>>>(bufD, bktPR, cntPR, NNODE, bufF);
    launch_gemm3(bufE, bufF, bufD, Bq2, bq2, bufB, 768, false, stream);

    // ---- edge classifiers (2 edges/wave) ----
    edge_dot<<<(EL * 32 + 255) / 256, 256, 0, stream>>>(bufA, bufB, eli_het,  eli_het  + EL, EL, out);
    edge_dot<<<(EL * 32 + 255) / 256, 256, 0, stream>>>(bufB, bufB, eli_homo, eli_homo + EL, EL, out + EL);
}

// Round 11
// 720.781 us; speedup vs baseline: 1.2614x; 1.2614x over previous
//
#include <hip/hip_runtime.h>

using u16 = unsigned short;
using u32 = unsigned int;

#define H 256
#define NNODE 50000
#define CAP 32        // Poisson(6): P(deg>32) ~ 1e-15
#define BM 128
#define BN 128
#define BK 64         // bf16 elems per K tile = 128 bytes/row
#define FINK 1280
#define NB 1563       // ceil(50000/32) 32-row blocks in tiled x layout

typedef __attribute__((ext_vector_type(8))) short bf16x8;
typedef __attribute__((ext_vector_type(4))) float f32x4;

struct AChunks { const void* p[3]; };

__device__ __forceinline__ u16 f2b(float f) {        // f32 -> bf16 RNE
    u32 u = __builtin_bit_cast(u32, f);
    return (u16)((u + 0x7FFFu + ((u >> 16) & 1u)) >> 16);
}
__device__ __forceinline__ float b2f(u16 h) {
    u32 u = ((u32)h) << 16;
    return __builtin_bit_cast(float, u);
}
__device__ __forceinline__ void gld_lds16(const void* g, void* l) {
    __builtin_amdgcn_global_load_lds(
        (__attribute__((address_space(1))) void*)(void*)g,
        (__attribute__((address_space(3))) void*)l, 16, 0, 0);
}
__device__ __forceinline__ u32 packbf(float a, float b) {
    return (u32)f2b(a) | ((u32)f2b(b) << 16);
}

// ---------------------------------------------------------------------------
// Pipelined bf16 MFMA GEMM: C[M,256] = concat_K(A) @ Bw[256,Ktot]^T
// 128x128 tile, BK=64, 512 threads (8 waves, 2m x 4n), dbuf LDS, vmcnt(4).
// TILED=false: A chunks are row-major [M][256] bf16 (H-GEMMs).  [PROVEN]
// TILED=true : A is [ktile][NB][32][64] bf16 (projection).      [PROVEN R7: 83us]
// ---------------------------------------------------------------------------
template<bool TILED, bool RELU>
__global__ __launch_bounds__(512) void gemm_pipe(
    AChunks ac, int aStride, const u16* __restrict__ Bw,
    const float* __restrict__ bias, u16* __restrict__ C, int M, int Ktot)
{
    __shared__ __align__(16) char As[2][BM * 128];
    __shared__ __align__(16) char Bs[2][BN * 128];

    const int tid = threadIdx.x;
    const int l   = tid & 63;
    const int w   = tid >> 6;          // 0..7
    const int wr  = w >> 2, wc = w & 3;
    const int m0  = blockIdx.x * BM;
    const int n0  = blockIdx.y * BN;
    const int nk  = Ktot >> 6;

    f32x4 acc[4][2];
#pragma unroll
    for (int i = 0; i < 4; ++i)
#pragma unroll
        for (int j = 0; j < 2; ++j) acc[i][j] = f32x4{0.f, 0.f, 0.f, 0.f};

    auto stageB = [&](int k, int bi) {
        int k0 = k * 64;
#pragma unroll
        for (int i = 0; i < 2; ++i) {
            int ci = i * 512 + tid;
            int r = ci >> 3, c16 = ci & 7;
            int sb = (c16 * 16) ^ ((r & 7) << 4);      // pre-swizzled source
            const u16* g = Bw + (size_t)(n0 + r) * Ktot + k0 + (sb >> 1);
            gld_lds16(g, &Bs[bi][ci * 16]);
        }
    };
    auto stageA = [&](int k, int bi) {
        if (!TILED) {
            int k0 = k * 64;
            const u16* base = (const u16*)ac.p[k0 >> 8];
            int kk = k0 & 255;
#pragma unroll
            for (int i = 0; i < 2; ++i) {
                int ci = i * 512 + tid;
                int r = ci >> 3, c16 = ci & 7;
                int row = m0 + r; row = row < M ? row : M - 1;
                int sb = (c16 * 16) ^ ((r & 7) << 4);
                const u16* g = base + (size_t)row * aStride + kk + (sb >> 1);
                gld_lds16(g, &As[bi][ci * 16]);
            }
        } else {
            const u16* base = (const u16*)ac.p[0];
#pragma unroll
            for (int i = 0; i < 2; ++i) {
                int ci = i * 512 + tid;
                int r = ci >> 3, c16 = ci & 7;
                int R = m0 + r; R = R < M ? R : M - 1;
                int sb = (c16 * 16) ^ ((R & 7) << 4);
                const u16* g = base + ((size_t)k * NB + (R >> 5)) * 2048
                                    + (R & 31) * 64 + (sb >> 1);
                gld_lds16(g, &As[bi][ci * 16]);
            }
        }
    };
    auto compute = [&](int bi) {
#pragma unroll
        for (int ks = 0; ks < 2; ++ks) {
            bf16x8 af[4], bfr[2];
#pragma unroll
            for (int mi = 0; mi < 4; ++mi) {
                int r = wr * 64 + mi * 16 + (l & 15);
                int off = (ks * 64 + (l >> 4) * 16) ^ ((r & 7) << 4);
                af[mi] = *(const bf16x8*)&As[bi][r * 128 + off];
            }
#pragma unroll
            for (int ni = 0; ni < 2; ++ni) {
                int r = wc * 32 + ni * 16 + (l & 15);
                int off = (ks * 64 + (l >> 4) * 16) ^ ((r & 7) << 4);
                bfr[ni] = *(const bf16x8*)&Bs[bi][r * 128 + off];
            }
#pragma unroll
            for (int mi = 0; mi < 4; ++mi)
#pragma unroll
                for (int ni = 0; ni < 2; ++ni)
                    acc[mi][ni] = __builtin_amdgcn_mfma_f32_16x16x32_bf16(
                        af[mi], bfr[ni], acc[mi][ni], 0, 0, 0);
        }
    };
    auto body = [&](int k, int cur) {
        asm volatile("s_waitcnt vmcnt(4)" ::: "memory");   // set(k) done
        __builtin_amdgcn_sched_barrier(0);
        __builtin_amdgcn_s_barrier();
        __builtin_amdgcn_sched_barrier(0);
        compute(cur);
        __builtin_amdgcn_sched_barrier(0);
        __builtin_amdgcn_s_barrier();
        __builtin_amdgcn_sched_barrier(0);
        int kq = k + 2; if (kq > nk - 1) kq = nk - 1;  // clamped dup keeps count
        stageB(kq, cur);
        stageA(kq, cur);
        __builtin_amdgcn_sched_barrier(0);
    };

    stageB(0, 0); stageA(0, 0);
    __builtin_amdgcn_sched_barrier(0);
    stageB(1, 1); stageA(1, 1);
    __builtin_amdgcn_sched_barrier(0);
    for (int k = 0; k < nk; k += 2) {   // nk even for all our shapes
        body(k,     0);
        body(k + 1, 1);
    }

    // epilogue: C/D layout col=lane&15, row=(lane>>4)*4+reg
    const int fr = l & 15, fq = l >> 4;
#pragma unroll
    for (int ni = 0; ni < 2; ++ni) {
        int col = n0 + wc * 32 + ni * 16 + fr;
        float bv = bias ? bias[col] : 0.f;
#pragma unroll
        for (int mi = 0; mi < 4; ++mi) {
            int rowb = m0 + wr * 64 + mi * 16 + fq * 4;
#pragma unroll
            for (int j = 0; j < 4; ++j) {
                int row = rowb + j;
                if (row < M) {
                    float v = acc[mi][ni][j] + bv;
                    if (RELU) v = fmaxf(v, 0.f);
                    C[(size_t)row * H + col] = f2b(v);
                }
            }
        }
    }
}

// ---------------------------------------------------------------------------
// cvt_direct: x f32 [M][1280] -> xb bf16 [20][NB][32][64], NO LDS.
// block = one (ktile t = blockIdx.y, rowblock rb = blockIdx.x).
// thread (r = tid>>3, k16 = tid&7): reads 32B contiguous f32, writes 16B;
// block writes 4 KB fully contiguous; 8 lanes read 256B contiguous per row.
// ---------------------------------------------------------------------------
__global__ __launch_bounds__(256) void cvt_direct(
    const float* __restrict__ in, u16* __restrict__ outp, int M)
{
    const int rb = blockIdx.x, t = blockIdx.y;
    const int r = threadIdx.x >> 3, k16 = threadIdx.x & 7;
    int row = rb * 32 + r; row = row < M ? row : M - 1;
    const float* src = in + (size_t)row * FINK + t * 64 + k16 * 8;
    float4 v0 = *(const float4*)src;
    float4 v1 = *(const float4*)(src + 4);
    uint4 o;
    o.x = packbf(v0.x, v0.y);
    o.y = packbf(v0.z, v0.w);
    o.z = packbf(v1.x, v1.y);
    o.w = packbf(v1.z, v1.w);
    u16* dst = outp + ((size_t)t * NB + rb) * 2048 + r * 64 + k16 * 8;
    *(uint4*)dst = o;
}

// ---------------------------------------------------------------------------
// utility kernels
// ---------------------------------------------------------------------------
__global__ __launch_bounds__(256) void fill_zero(float4* __restrict__ p, size_t n4)
{
    size_t i = (size_t)blockIdx.x * blockDim.x + threadIdx.x;
    size_t stride = (size_t)gridDim.x * blockDim.x;
    for (; i < n4; i += stride) p[i] = make_float4(0.f, 0.f, 0.f, 0.f);
}

__global__ __launch_bounds__(256) void build_bucket(
    const int* __restrict__ src, const int* __restrict__ dst, int nE,
    int* __restrict__ cnt, int* __restrict__ bucket)
{
    int i = blockIdx.x * blockDim.x + threadIdx.x;
    if (i >= nE) return;
    int d = dst[i];
    int pos = atomicAdd(&cnt[d], 1);
    if (pos < CAP) bucket[(size_t)d * CAP + pos] = src[i];
}

__global__ __launch_bounds__(256) void seg_mean_gather(
    const u16* __restrict__ feat, const int* __restrict__ bucket,
    const int* __restrict__ cnt, int n_dst, u16* __restrict__ out)
{
    int d = (int)(((size_t)blockIdx.x * blockDim.x + threadIdx.x) >> 6);
    int lane = threadIdx.x & 63;
    if (d >= n_dst) return;
    int c = cnt[d];
    int cc = c < CAP ? c : CAP;
    const int* b = bucket + (size_t)d * CAP;
    float a0 = 0.f, a1 = 0.f, a2 = 0.f, a3 = 0.f;
    int i = 0;
    for (; i + 4 <= cc; i += 4) {            // 4 gathers in flight
        int s0 = b[i], s1 = b[i + 1], s2 = b[i + 2], s3 = b[i + 3];
        uint2 v0 = *(const uint2*)(feat + (size_t)s0 * H + lane * 4);
        uint2 v1 = *(const uint2*)(feat + (size_t)s1 * H + lane * 4);
        uint2 v2 = *(const uint2*)(feat + (size_t)s2 * H + lane * 4);
        uint2 v3 = *(const uint2*)(feat + (size_t)s3 * H + lane * 4);
        a0 += b2f((u16)(v0.x & 0xffff)) + b2f((u16)(v1.x & 0xffff))
            + b2f((u16)(v2.x & 0xffff)) + b2f((u16)(v3.x & 0xffff));
        a1 += b2f((u16)(v0.x >> 16)) + b2f((u16)(v1.x >> 16))
            + b2f((u16)(v2.x >> 16)) + b2f((u16)(v3.x >> 16));
        a2 += b2f((u16)(v0.y & 0xffff)) + b2f((u16)(v1.y & 0xffff))
            + b2f((u16)(v2.y & 0xffff)) + b2f((u16)(v3.y & 0xffff));
        a3 += b2f((u16)(v0.y >> 16)) + b2f((u16)(v1.y >> 16))
            + b2f((u16)(v2.y >> 16)) + b2f((u16)(v3.y >> 16));
    }
    for (; i < cc; ++i) {
        uint2 v = *(const uint2*)(feat + (size_t)b[i] * H + lane * 4);
        a0 += b2f((u16)(v.x & 0xffff));
        a1 += b2f((u16)(v.x >> 16));
        a2 += b2f((u16)(v.y & 0xffff));
        a3 += b2f((u16)(v.y >> 16));
    }
    float inv = 1.0f / fmaxf((float)c, 1.0f);
    uint2 o;
    o.x = packbf(a0 * inv, a1 * inv);
    o.y = packbf(a2 * inv, a3 * inv);
    *(uint2*)(out + (size_t)d * H + lane * 4) = o;
}

// 2 edges per wave: 32 lanes x 16B per edge row
__global__ __launch_bounds__(256) void edge_dot(
    const u16* __restrict__ P, const u16* __restrict__ Q,
    const int* __restrict__ ia, const int* __restrict__ ib,
    int nE, float* __restrict__ out)
{
    int gi = blockIdx.x * 256 + threadIdx.x;
    int e = gi >> 5, l32 = gi & 31;
    if (e >= nE) return;
    uint4 a = *(const uint4*)(P + (size_t)ia[e] * H + l32 * 8);
    uint4 b = *(const uint4*)(Q + (size_t)ib[e] * H + l32 * 8);
    float v = 0.f;
    v += b2f((u16)(a.x & 0xffff)) * b2f((u16)(b.x & 0xffff));
    v += b2f((u16)(a.x >> 16))    * b2f((u16)(b.x >> 16));
    v += b2f((u16)(a.y & 0xffff)) * b2f((u16)(b.y & 0xffff));
    v += b2f((u16)(a.y >> 16))    * b2f((u16)(b.y >> 16));
    v += b2f((u16)(a.z & 0xffff)) * b2f((u16)(b.z & 0xffff));
    v += b2f((u16)(a.z >> 16))    * b2f((u16)(b.z >> 16));
    v += b2f((u16)(a.w & 0xffff)) * b2f((u16)(b.w & 0xffff));
    v += b2f((u16)(a.w >> 16))    * b2f((u16)(b.w >> 16));
#pragma unroll
    for (int off = 16; off; off >>= 1) v += __shfl_xor(v, off);
    if (l32 == 0) out[e] = v;
}

// fused weight pack: 12 items, 1024 elems per block
struct PackTab {
    const float* s1[12]; const float* s2[12]; u16* dst[12];
    int Ks[12], Kdst[12], koff[12], blk0[13];
};
__global__ __launch_bounds__(256) void pack_all(PackTab t)
{
    int b = blockIdx.x;
    int it = 0;
    while (it < 11 && b >= t.blk0[it + 1]) ++it;
    int idx = (b - t.blk0[it]) * 1024 + threadIdx.x * 4;
    int Ks = t.Ks[it];
    if (idx >= 256 * Ks) return;
    int n = idx / Ks;
    int k = idx - n * Ks;
    float4 v = *(const float4*)(t.s1[it] + idx);
    if (t.s2[it]) {
        float4 u = *(const float4*)(t.s2[it] + idx);
        v.x += u.x; v.y += u.y; v.z += u.z; v.w += u.w;
    }
    ushort4 h;
    h.x = f2b(v.x); h.y = f2b(v.y); h.z = f2b(v.z); h.w = f2b(v.w);
    *(ushort4*)(t.dst[it] + (size_t)n * t.Kdst[it] + t.koff[it] + k) = h;
}

__global__ void bias_pair(const float* __restrict__ bl1, const float* __restrict__ bl2,
                          float* __restrict__ bq1, float* __restrict__ bq2)
{
    int i = threadIdx.x;
    if (blockIdx.x == 0) bq1[i] = bl1[i] + bl1[512 + i];
    else                 bq2[i] = bl2[i] + bl2[512 + i];
}

// ---------------------------------------------------------------------------
// host-side helpers
// ---------------------------------------------------------------------------
static inline void launch_gemm3(const void* a0, const void* a1, const void* a2,
                                const u16* Bw, const float* bias, u16* C,
                                int Ktot, bool relu, hipStream_t s)
{
    AChunks ac = {{a0, a1, a2}};
    dim3 grid((NNODE + BM - 1) / BM, H / BN);
    if (relu) gemm_pipe<false, true><<<grid, 512, 0, s>>>(ac, 256, Bw, bias, C, NNODE, Ktot);
    else      gemm_pipe<false, false><<<grid, 512, 0, s>>>(ac, 256, Bw, bias, C, NNODE, Ktot);
}

extern "C" void kernel_launch(void* const* d_in, const int* in_sizes, int n_in,
                              void* d_out, int out_size, void* d_ws, size_t ws_size,
                              hipStream_t stream)
{
    const float* x_pep  = (const float*)d_in[0];
    const float* x_prot = (const float*)d_in[1];
    const float* Wpep   = (const float*)d_in[2];
    const float* bpep   = (const float*)d_in[3];
    const float* Wprot  = (const float*)d_in[4];
    const float* bprot  = (const float*)d_in[5];
    const float* Wl1    = (const float*)d_in[6];
    const float* bl1    = (const float*)d_in[7];
    const float* Wr1    = (const float*)d_in[8];
    const float* Wl2    = (const float*)d_in[9];
    const float* bl2    = (const float*)d_in[10];
    const float* Wr2    = (const float*)d_in[11];
    const int* ei_pp    = (const int*)d_in[12];
    const int* ei_rp    = (const int*)d_in[13];
    const int* ei_prot  = (const int*)d_in[14];
    const int* eli_het  = (const int*)d_in[15];
    const int* eli_homo = (const int*)d_in[16];

    const int E  = in_sizes[12] / 2;   // 300000
    const int EL = in_sizes[15] / 2;   // 200000

    float* out = (float*)d_out;

    // ---- workspace carve (~435 MB of 1 GB) ----
    const size_t nodeElems = (size_t)NNODE * H;      // bf16 elems
    u16* bufA = (u16*)d_ws;            // h_pep  -> p2
    u16* bufB = bufA + nodeElems;      // h_prot -> q2
    u16* bufC = bufB + nodeElems;      // p1
    u16* bufD = bufC + nodeElems;      // q1
    u16* bufE = bufD + nodeElems;      // mean scratch 1
    u16* bufF = bufE + nodeElems;      // mean scratch 2
    u16* Bpep  = bufF + nodeElems;
    u16* Bprot = Bpep  + (size_t)256 * 1280;
    u16* Bp1   = Bprot + (size_t)256 * 1280;
    u16* Bq1   = Bp1   + (size_t)256 * 512;
    u16* Bp2   = Bq1   + (size_t)256 * 768;
    u16* Bq2   = Bp2   + (size_t)256 * 512;
    float* bq1 = (float*)(Bq2 + (size_t)256 * 768);
    float* bq2 = bq1 + 256;
    int* cntRP   = (int*)(bq2 + 256);
    int* cntPP   = cntRP + NNODE;
    int* cntPR   = cntPP + NNODE;
    int* bktRP   = cntPR + NNODE;
    int* bktPP   = bktRP + (size_t)NNODE * CAP;
    int* bktPR   = bktPP + (size_t)NNODE * CAP;
    u16* xbPep   = (u16*)(bktPR + (size_t)NNODE * CAP);   // 20*NB*2048 u16 = 128.1 MB
    u16* xbProt  = xbPep + (size_t)20 * NB * 2048;

    const size_t HH = (size_t)H * H;

    // ---- fused weight pack ----
    PackTab t{};
    int blk = 0, it = 0;
    auto add = [&](const float* s1, const float* s2, u16* d, int Ks, int Kd, int ko) {
        t.s1[it] = s1; t.s2[it] = s2; t.dst[it] = d;
        t.Ks[it] = Ks; t.Kdst[it] = Kd; t.koff[it] = ko;
        t.blk0[it] = blk; blk += (256 * Ks) / 1024; ++it;
    };
    add(Wpep,  nullptr, Bpep,  1280, 1280, 0);
    add(Wprot, nullptr, Bprot, 1280, 1280, 0);
    add(Wl1 + 1 * HH, nullptr,      Bp1, 256, 512, 0);
    add(Wr1 + 1 * HH, nullptr,      Bp1, 256, 512, 256);
    add(Wl1 + 0 * HH, nullptr,      Bq1, 256, 768, 0);
    add(Wl1 + 2 * HH, nullptr,      Bq1, 256, 768, 256);
    add(Wr1 + 0 * HH, Wr1 + 2 * HH, Bq1, 256, 768, 512);
    add(Wl2 + 1 * HH, nullptr,      Bp2, 256, 512, 0);
    add(Wr2 + 1 * HH, nullptr,      Bp2, 256, 512, 256);
    add(Wl2 + 0 * HH, nullptr,      Bq2, 256, 768, 0);
    add(Wl2 + 2 * HH, nullptr,      Bq2, 256, 768, 256);
    add(Wr2 + 0 * HH, Wr2 + 2 * HH, Bq2, 256, 768, 512);
    t.blk0[12] = blk;
    pack_all<<<blk, 256, 0, stream>>>(t);
    bias_pair<<<2, 256, 0, stream>>>(bl1, bl2, bq1, bq2);

    // ---- buckets: built ONCE per edge type, reused by both layers ----
    fill_zero<<<147, 256, 0, stream>>>((float4*)cntRP, (size_t)3 * NNODE / 4);
    build_bucket<<<(E + 255) / 256, 256, 0, stream>>>(ei_rp,   ei_rp + E,   E, cntRP, bktRP);
    build_bucket<<<(E + 255) / 256, 256, 0, stream>>>(ei_pp,   ei_pp + E,   E, cntPP, bktPP);
    build_bucket<<<(E + 255) / 256, 256, 0, stream>>>(ei_prot, ei_prot + E, E, cntPR, bktPR);

    // ---- input projections: LDS-free tiling convert + tiled-A gemm_pipe ----
    {
        dim3 grid((NNODE + BM - 1) / BM, H / BN);
        dim3 cgrid(NB, 20);
        AChunks ap = {{xbPep, nullptr, nullptr}};
        AChunks aq = {{xbProt, nullptr, nullptr}};
        cvt_direct<<<cgrid, 256, 0, stream>>>(x_pep, xbPep, NNODE);
        gemm_pipe<true, false><<<grid, 512, 0, stream>>>(ap, 0, Bpep, bpep, bufA, NNODE, FINK);
        cvt_direct<<<cgrid, 256, 0, stream>>>(x_prot, xbProt, NNODE);
        gemm_pipe<true, false><<<grid, 512, 0, stream>>>(aq, 0, Bprot, bprot, bufB, NNODE, FINK);
    }

    const int gG = (NNODE * 64 + 255) / 256;
    // ---- layer 1 ----
    seg_mean_gather<<<gG, 256, 0, stream>>>(bufB, bktRP, cntRP, NNODE, bufE);
    launch_gemm3(bufE, bufA, nullptr, Bp1, bl1 + 256, bufC, 512, true, stream);
    seg_mean_gather<<<gG, 256, 0, stream>>>(bufA, bktPP, cntPP, NNODE, bufE);
    seg_mean_gather<<<gG, 256, 0, stream>>>(bufB, bktPR, cntPR, NNODE, bufF);
    launch_gemm3(bufE, bufF, bufB, Bq1, bq1, bufD, 768, true, stream);

    // ---- layer 2 ----
    seg_mean_gather<<<gG, 256, 0, stream>>>(bufD, bktRP, cntRP, NNODE, bufE);
    launch_gemm3(bufE, bufC, nullptr, Bp2, bl2 + 256, bufA, 512, false, stream);
    seg_mean_gather<<<gG, 256, 0, stream>>>(bufC, bktPP, cntPP, NNODE, bufE);
    seg_mean_gather<<<gG, 256, 0, stream>>>(bufD, bktPR, cntPR, NNODE, bufF);
    launch_gemm3(bufE, bufF, bufD, Bq2, bq2, bufB, 768, false, stream);

    // ---- edge classifiers (2 edges/wave) ----
    edge_dot<<<(EL * 32 + 255) / 256, 256, 0, stream>>>(bufA, bufB, eli_het,  eli_het  + EL, EL, out);
    edge_dot<<<(EL * 32 + 255) / 256, 256, 0, stream>>>(bufB, bufB, eli_homo, eli_homo + EL, EL, out + EL);
}